// Round 1
// baseline (419.759 us; speedup 1.0000x reference)
//
#include <hip/hip_runtime.h>
#include <hip/hip_bf16.h>

// ---------------------------------------------------------------------------
// TransformerLayer on MI355X (gfx950), bf16 MFMA pipeline.
// S=4096, D_MODEL=1024, D_INTERNAL=4096. Outputs: out[S,D] ++ attn[S,S], fp32.
// ---------------------------------------------------------------------------

typedef __attribute__((ext_vector_type(4))) float  f32x4;
typedef __attribute__((ext_vector_type(8))) short  bf16x8;
typedef __attribute__((ext_vector_type(4))) unsigned short us4;
typedef __attribute__((ext_vector_type(8))) unsigned short us8;

#define DEVINL __device__ __forceinline__

static constexpr int S   = 4096;
static constexpr int DM  = 1024;
static constexpr int DI  = 4096;

DEVINL unsigned short f2bf(float f) {
  union { float f; unsigned u; } v; v.f = f;
  unsigned r = v.u + 0x7fffu + ((v.u >> 16) & 1u);   // RNE
  return (unsigned short)(r >> 16);
}

DEVINL void gld_lds16(const unsigned short* g, unsigned short* l) {
  __builtin_amdgcn_global_load_lds(
      (const __attribute__((address_space(1))) void*)g,
      (__attribute__((address_space(3))) void*)l,
      16, 0, 0);
}

// ---------------------------------------------------------------------------
// fp32 -> bf16 elementwise convert (8 elems / thread)
// ---------------------------------------------------------------------------
__global__ void cvt_f32_bf16(const float* __restrict__ in,
                             unsigned short* __restrict__ out, long n) {
  long i = ((long)blockIdx.x * 256 + threadIdx.x) * 8;
  if (i >= n) return;
  f32x4 a = *(const f32x4*)(in + i);
  f32x4 b = *(const f32x4*)(in + i + 4);
  us8 o;
  o[0] = f2bf(a[0]); o[1] = f2bf(a[1]); o[2] = f2bf(a[2]); o[3] = f2bf(a[3]);
  o[4] = f2bf(b[0]); o[5] = f2bf(b[1]); o[6] = f2bf(b[2]); o[7] = f2bf(b[3]);
  *(us8*)(out + i) = o;
}

// ---------------------------------------------------------------------------
// fp32 [R][C] -> bf16 [C][R] transpose+convert. 32x32 tiles, block (32,8).
// ---------------------------------------------------------------------------
__global__ void transpose_cvt(const float* __restrict__ in,
                              unsigned short* __restrict__ out, int R, int C) {
  __shared__ float tile[32][33];
  const int bx = blockIdx.x * 32;   // col base (in input)
  const int by = blockIdx.y * 32;   // row base (in input)
  const int tx = threadIdx.x, ty = threadIdx.y;
  #pragma unroll
  for (int j = 0; j < 4; ++j) {
    int r = ty + j * 8;
    tile[r][tx] = in[(size_t)(by + r) * C + bx + tx];
  }
  __syncthreads();
  #pragma unroll
  for (int j = 0; j < 4; ++j) {
    int r = ty + j * 8;                       // output-row-within-tile = input col
    out[(size_t)(bx + r) * R + by + tx] = f2bf(tile[tx][r]);
  }
}

// ---------------------------------------------------------------------------
// Tiled bf16 GEMM: C = A[M,K] @ Bt[N,K]^T, fp32 accum, templated epilogue.
// 128x128 tile, BK=32, 256 threads (4 waves, each 64x64 = 4x4 frags 16x16x32).
// global_load_lds width-16 staging, linear LDS (m97 structure).
// ---------------------------------------------------------------------------
enum { EPI_QKV = 0, EPI_VT = 1, EPI_SC = 2, EPI_H = 3, EPI_FF1 = 4, EPI_OUT = 5 };

template <int EPI, bool TRI_SKIP>
__launch_bounds__(256)
__global__ void gemm_bt(const unsigned short* __restrict__ A,
                        const unsigned short* __restrict__ Bt,
                        int M, int N, int K,
                        const float* __restrict__ bias,
                        const float* __restrict__ res,
                        float* __restrict__ Cf,
                        unsigned short* __restrict__ Cb,
                        float scale) {
  const int bm0 = blockIdx.y * 128;
  const int bn0 = blockIdx.x * 128;
  if (TRI_SKIP && bn0 > bm0 + 127) return;   // fully-masked causal tile

  __shared__ __align__(16) unsigned short As[128 * 32];
  __shared__ __align__(16) unsigned short Bs[128 * 32];

  const int tid  = threadIdx.x;
  const int lane = tid & 63;
  const int w    = tid >> 6;          // wave 0..3
  const int wr   = w >> 1, wc = w & 1;

  f32x4 acc[4][4] = {};

  // staging: per wave, 2 instructions for A + 2 for B; 64 lanes x 16B each.
  const int srow = w * 16 + (lane >> 2);      // 0..63 across the block
  const int scol = (lane & 3) * 8;            // 8 bf16 = 16B chunks

  const unsigned short* Aptr0 = A  + (size_t)(bm0 + srow)      * K + scol;
  const unsigned short* Aptr1 = A  + (size_t)(bm0 + srow + 64) * K + scol;
  const unsigned short* Bptr0 = Bt + (size_t)(bn0 + srow)      * K + scol;
  const unsigned short* Bptr1 = Bt + (size_t)(bn0 + srow + 64) * K + scol;

  unsigned short* AsW0 = As + w * 512;          // bytes: w*1024
  unsigned short* AsW1 = As + 2048 + w * 512;   // bytes: 4096 + w*1024
  unsigned short* BsW0 = Bs + w * 512;
  unsigned short* BsW1 = Bs + 2048 + w * 512;

  // fragment read bases
  const int fr = lane & 15;   // frag row/col
  const int fq = lane >> 4;   // quad
  const unsigned short* ArdBase = As + (wr * 64 + fr) * 32 + fq * 8;
  const unsigned short* BrdBase = Bs + (wc * 64 + fr) * 32 + fq * 8;

  const int nK = K >> 5;
  for (int kt = 0; kt < nK; ++kt) {
    __syncthreads();
    gld_lds16(Aptr0, AsW0);
    gld_lds16(Aptr1, AsW1);
    gld_lds16(Bptr0, BsW0);
    gld_lds16(Bptr1, BsW1);
    __syncthreads();

    bf16x8 a[4], b[4];
    #pragma unroll
    for (int i = 0; i < 4; ++i) {
      a[i] = *(const bf16x8*)(ArdBase + i * 512);
      b[i] = *(const bf16x8*)(BrdBase + i * 512);
    }
    #pragma unroll
    for (int mi = 0; mi < 4; ++mi)
      #pragma unroll
      for (int ni = 0; ni < 4; ++ni)
        acc[mi][ni] = __builtin_amdgcn_mfma_f32_16x16x32_bf16(
            a[mi], b[ni], acc[mi][ni], 0, 0, 0);

    Aptr0 += 32; Aptr1 += 32; Bptr0 += 32; Bptr1 += 32;
  }

  // epilogue: C/D layout col = lane&15, row = (lane>>4)*4 + reg
  const int row0 = bm0 + wr * 64 + fq * 4;
  const int col0 = bn0 + wc * 64 + fr;
  #pragma unroll
  for (int ni = 0; ni < 4; ++ni) {
    const int col = col0 + ni * 16;
    float bval = 0.f;
    if (EPI == EPI_QKV || EPI == EPI_FF1 || EPI == EPI_OUT) bval = bias[col];
    #pragma unroll
    for (int mi = 0; mi < 4; ++mi) {
      #pragma unroll
      for (int j = 0; j < 4; ++j) {
        const int row = row0 + mi * 16 + j;
        const size_t idx = (size_t)row * N + col;
        const float c = acc[mi][ni][j];
        if (EPI == EPI_QKV) {
          Cb[idx] = f2bf(c + bval);
        } else if (EPI == EPI_VT) {
          Cb[idx] = f2bf(c + bias[row]);
        } else if (EPI == EPI_SC) {
          Cf[idx] = c * scale;
        } else if (EPI == EPI_H) {
          const float hv = c + res[idx];
          Cf[idx] = hv;
          Cb[idx] = f2bf(hv);
        } else if (EPI == EPI_FF1) {
          const float r = c + bval;
          Cb[idx] = f2bf(r > 0.f ? r : 0.f);
        } else {  // EPI_OUT
          Cf[idx] = c + bval + res[idx];
        }
      }
    }
  }
}

// ---------------------------------------------------------------------------
// Causal row softmax, in-place on fp32 scores (d_out attn region), plus bf16
// copy. One block (256 thr) per row; row cached in 16 regs/thread.
// ---------------------------------------------------------------------------
__global__ void softmax_rows(float* __restrict__ sc,
                             unsigned short* __restrict__ attnb) {
  const int m = blockIdx.x;
  const int tid = threadIdx.x;
  const int valid = m + 1;
  float* rowf = sc + (size_t)m * S;
  unsigned short* rowb = attnb + (size_t)m * S;

  f32x4 v[4];
  float lmax = -1e30f;
  #pragma unroll
  for (int i = 0; i < 4; ++i) {
    const int idx = tid * 4 + i * 1024;
    v[i] = *(const f32x4*)(rowf + idx);
    #pragma unroll
    for (int j = 0; j < 4; ++j)
      if (idx + j < valid) lmax = fmaxf(lmax, v[i][j]);
  }
  #pragma unroll
  for (int off = 32; off > 0; off >>= 1)
    lmax = fmaxf(lmax, __shfl_xor(lmax, off, 64));

  __shared__ float red[8];
  if ((tid & 63) == 0) red[tid >> 6] = lmax;
  __syncthreads();
  lmax = fmaxf(fmaxf(red[0], red[1]), fmaxf(red[2], red[3]));

  f32x4 e[4];
  float lsum = 0.f;
  #pragma unroll
  for (int i = 0; i < 4; ++i) {
    const int idx = tid * 4 + i * 1024;
    #pragma unroll
    for (int j = 0; j < 4; ++j) {
      const float ev = (idx + j < valid) ? __expf(v[i][j] - lmax) : 0.f;
      e[i][j] = ev;
      lsum += ev;
    }
  }
  #pragma unroll
  for (int off = 32; off > 0; off >>= 1)
    lsum += __shfl_xor(lsum, off, 64);
  if ((tid & 63) == 0) red[4 + (tid >> 6)] = lsum;
  __syncthreads();
  const float tsum = red[4] + red[5] + red[6] + red[7];
  const float inv = 1.0f / tsum;

  #pragma unroll
  for (int i = 0; i < 4; ++i) {
    const int idx = tid * 4 + i * 1024;
    f32x4 o; us4 ob;
    #pragma unroll
    for (int j = 0; j < 4; ++j) {
      const float t = e[i][j] * inv;
      o[j] = t;
      ob[j] = f2bf(t);
    }
    *(f32x4*)(rowf + idx) = o;
    *(us4*)(rowb + idx) = ob;
  }
}

// ---------------------------------------------------------------------------
extern "C" void kernel_launch(void* const* d_in, const int* in_sizes, int n_in,
                              void* d_out, int out_size, void* d_ws, size_t ws_size,
                              hipStream_t stream) {
  const float* x  = (const float*)d_in[0];
  const float* Wq = (const float*)d_in[1];
  const float* bq = (const float*)d_in[2];
  const float* Wk = (const float*)d_in[3];
  const float* bk = (const float*)d_in[4];
  const float* Wv = (const float*)d_in[5];
  const float* bv = (const float*)d_in[6];
  const float* W1 = (const float*)d_in[7];
  const float* b1 = (const float*)d_in[8];
  const float* W2 = (const float*)d_in[9];
  const float* b2 = (const float*)d_in[10];
  (void)in_sizes; (void)n_in; (void)out_size; (void)ws_size;

  float* outp  = (float*)d_out;                       // [S, DM]
  float* attnf = (float*)d_out + (size_t)S * DM;      // [S, S]

  const size_t MB = 1ull << 20;
  char* ws = (char*)d_ws;
  unsigned short* xb    = (unsigned short*)(ws + 0 * MB);    // 8 MB  [S,DM]
  unsigned short* Wqt   = (unsigned short*)(ws + 8 * MB);    // 2 MB  [DM,DM]
  unsigned short* Wkt   = (unsigned short*)(ws + 10 * MB);   // 2 MB
  unsigned short* Wvt   = (unsigned short*)(ws + 12 * MB);   // 2 MB
  unsigned short* W1t   = (unsigned short*)(ws + 14 * MB);   // 8 MB  [DI,DM]
  unsigned short* W2t   = (unsigned short*)(ws + 22 * MB);   // 8 MB  [DM,DI]
  unsigned short* qb    = (unsigned short*)(ws + 30 * MB);   // 8 MB  [S,DM]
  unsigned short* kb    = (unsigned short*)(ws + 38 * MB);   // 8 MB  [S,DM]
  unsigned short* vt    = (unsigned short*)(ws + 46 * MB);   // 8 MB  [DM,S]
  unsigned short* attnb = (unsigned short*)(ws + 54 * MB);   // 32 MB [S,S]
  float*          h     = (float*)(ws + 86 * MB);            // 16 MB [S,DM]
  unsigned short* hb    = (unsigned short*)(ws + 102 * MB);  // 8 MB  [S,DM]
  unsigned short* ff1b  = (unsigned short*)(ws + 54 * MB);   // reuse attnb region

  // 1) convert x to bf16
  cvt_f32_bf16<<<dim3((S * DM) / (256 * 8)), dim3(256), 0, stream>>>(x, xb, (long)S * DM);

  // 2) transpose+convert weights to [N,K] bf16
  transpose_cvt<<<dim3(DM / 32, DM / 32), dim3(32, 8), 0, stream>>>(Wq, Wqt, DM, DM);
  transpose_cvt<<<dim3(DM / 32, DM / 32), dim3(32, 8), 0, stream>>>(Wk, Wkt, DM, DM);
  transpose_cvt<<<dim3(DM / 32, DM / 32), dim3(32, 8), 0, stream>>>(Wv, Wvt, DM, DM);
  transpose_cvt<<<dim3(DI / 32, DM / 32), dim3(32, 8), 0, stream>>>(W1, W1t, DM, DI);
  transpose_cvt<<<dim3(DM / 32, DI / 32), dim3(32, 8), 0, stream>>>(W2, W2t, DI, DM);

  // 3) projections
  gemm_bt<EPI_QKV, false><<<dim3(DM / 128, S / 128), 256, 0, stream>>>(
      xb, Wqt, S, DM, DM, bq, nullptr, nullptr, qb, 1.f);
  gemm_bt<EPI_QKV, false><<<dim3(DM / 128, S / 128), 256, 0, stream>>>(
      xb, Wkt, S, DM, DM, bk, nullptr, nullptr, kb, 1.f);
  // vt[d][s] = sum_k Wv[k][d]*x[s][k] + bv[d]  (V stored transposed directly)
  gemm_bt<EPI_VT, false><<<dim3(S / 128, DM / 128), 256, 0, stream>>>(
      Wvt, xb, DM, S, DM, bv, nullptr, nullptr, vt, 1.f);

  // 4) scores = q @ k^T / 32, upper-triangle tiles skipped
  gemm_bt<EPI_SC, true><<<dim3(S / 128, S / 128), 256, 0, stream>>>(
      qb, kb, S, S, DM, nullptr, nullptr, attnf, nullptr, 0.03125f);

  // 5) causal softmax (in-place fp32 into d_out) + bf16 copy
  softmax_rows<<<dim3(S), dim3(256), 0, stream>>>(attnf, attnb);

  // 6) h = x + attn @ v   (fp32 h and bf16 hb)
  gemm_bt<EPI_H, false><<<dim3(DM / 128, S / 128), 256, 0, stream>>>(
      attnb, vt, S, DM, S, nullptr, x, h, hb, 1.f);

  // 7) ff1 = relu(h @ W1 + b1)  (bf16)
  gemm_bt<EPI_FF1, false><<<dim3(DI / 128, S / 128), 256, 0, stream>>>(
      hb, W1t, S, DI, DM, b1, nullptr, nullptr, ff1b, 1.f);

  // 8) out = h + ff1 @ W2 + b2  (fp32, into d_out)
  gemm_bt<EPI_OUT, false><<<dim3(DM / 128, S / 128), 256, 0, stream>>>(
      ff1b, W2t, S, DM, S, b2, h, outp, nullptr, 1.f);
}

// Round 2
// 330.322 us; speedup vs baseline: 1.2708x; 1.2708x over previous
//
#include <hip/hip_runtime.h>
#include <hip/hip_bf16.h>

// ---------------------------------------------------------------------------
// TransformerLayer on MI355X (gfx950), bf16 MFMA pipeline. Round 2:
// fused QKV, packed-triangular scores grid, tri-truncated + split-K PV,
// split-K FF2, lda/ldb-general 128x128 GEMM core (m97 structure).
// ---------------------------------------------------------------------------

typedef __attribute__((ext_vector_type(4))) float  f32x4;
typedef __attribute__((ext_vector_type(8))) short  bf16x8;
typedef __attribute__((ext_vector_type(4))) unsigned short us4;
typedef __attribute__((ext_vector_type(8))) unsigned short us8;

#define DEVINL __device__ __forceinline__

static constexpr int S   = 4096;
static constexpr int DM  = 1024;
static constexpr int DI  = 4096;

DEVINL unsigned short f2bf(float f) {
  union { float f; unsigned u; } v; v.f = f;
  unsigned r = v.u + 0x7fffu + ((v.u >> 16) & 1u);   // RNE
  return (unsigned short)(r >> 16);
}

DEVINL void gld_lds16(const unsigned short* g, unsigned short* l) {
  __builtin_amdgcn_global_load_lds(
      (const __attribute__((address_space(1))) void*)g,
      (__attribute__((address_space(3))) void*)l,
      16, 0, 0);
}

// ---------------------------------------------------------------------------
__global__ void cvt_f32_bf16(const float* __restrict__ in,
                             unsigned short* __restrict__ out, long n) {
  long i = ((long)blockIdx.x * 256 + threadIdx.x) * 8;
  if (i >= n) return;
  f32x4 a = *(const f32x4*)(in + i);
  f32x4 b = *(const f32x4*)(in + i + 4);
  us8 o;
  o[0] = f2bf(a[0]); o[1] = f2bf(a[1]); o[2] = f2bf(a[2]); o[3] = f2bf(a[3]);
  o[4] = f2bf(b[0]); o[5] = f2bf(b[1]); o[6] = f2bf(b[2]); o[7] = f2bf(b[3]);
  *(us8*)(out + i) = o;
}

// fp32 [R][C] -> bf16 [C][R]
__global__ void transpose_cvt(const float* __restrict__ in,
                              unsigned short* __restrict__ out, int R, int C) {
  __shared__ float tile[32][33];
  const int bx = blockIdx.x * 32, by = blockIdx.y * 32;
  const int tx = threadIdx.x, ty = threadIdx.y;
  #pragma unroll
  for (int j = 0; j < 4; ++j) {
    int r = ty + j * 8;
    tile[r][tx] = in[(size_t)(by + r) * C + bx + tx];
  }
  __syncthreads();
  #pragma unroll
  for (int j = 0; j < 4; ++j) {
    int r = ty + j * 8;
    out[(size_t)(bx + r) * R + by + tx] = f2bf(tile[tx][r]);
  }
}

// bf16 [R rows x C cols] (row stride ld) -> out[c*ldo + r]
__global__ void transpose_bf16(const unsigned short* __restrict__ in, int ld,
                               unsigned short* __restrict__ out, int ldo) {
  __shared__ unsigned short tile[32][33];
  const int bx = blockIdx.x * 32, by = blockIdx.y * 32;
  const int tx = threadIdx.x, ty = threadIdx.y;
  #pragma unroll
  for (int j = 0; j < 4; ++j) {
    int r = ty + j * 8;
    tile[r][tx] = in[(size_t)(by + r) * ld + bx + tx];
  }
  __syncthreads();
  #pragma unroll
  for (int j = 0; j < 4; ++j) {
    int r = ty + j * 8;
    out[(size_t)(bx + r) * ldo + by + tx] = tile[tx][r];
  }
}

// ---------------------------------------------------------------------------
// C = A[M,K](lda) @ Bt[N,K](ldb)^T. 128x128 tile, BK=32, 4 waves.
// ---------------------------------------------------------------------------
enum { EPI_QKV = 0, EPI_SC = 2, EPI_FF1 = 4, EPI_PART = 6 };

template <int EPI, bool TRI_PACK, bool TRI_TRUNC>
__launch_bounds__(256)
__global__ void gemm_bt(const unsigned short* __restrict__ A,
                        const unsigned short* __restrict__ Bt,
                        int M, int N, int K, int lda, int ldb, int kChunk,
                        const float* __restrict__ bias,
                        float* __restrict__ Cf,
                        unsigned short* __restrict__ Cb,
                        float scale) {
  int bm, bn;
  if (TRI_PACK) {
    int t = blockIdx.x;
    bm = (int)((sqrtf(8.f * (float)t + 1.f) - 1.f) * 0.5f);
    while ((bm + 1) * (bm + 2) / 2 <= t) ++bm;
    while (bm * (bm + 1) / 2 > t) --bm;
    bn = t - bm * (bm + 1) / 2;
  } else { bm = blockIdx.y; bn = blockIdx.x; }
  const int bm0 = bm * 128, bn0 = bn * 128;

  const int kbeg = blockIdx.z * kChunk;
  int kend = min(K, kbeg + kChunk);
  if (TRI_TRUNC) kend = min(kend, bm0 + 128);
  const int nK = (kend - kbeg) >> 5;    // may be <= 0 -> acc stays 0

  __shared__ __align__(16) unsigned short As[128 * 32];
  __shared__ __align__(16) unsigned short Bs[128 * 32];

  const int tid  = threadIdx.x;
  const int lane = tid & 63;
  const int w    = tid >> 6;
  const int wr   = w >> 1, wc = w & 1;

  f32x4 acc[4][4] = {};

  const int srow = w * 16 + (lane >> 2);
  const int scol = (lane & 3) * 8;

  const unsigned short* Aptr0 = A  + (size_t)(bm0 + srow)      * lda + kbeg + scol;
  const unsigned short* Aptr1 = A  + (size_t)(bm0 + srow + 64) * lda + kbeg + scol;
  const unsigned short* Bptr0 = Bt + (size_t)(bn0 + srow)      * ldb + kbeg + scol;
  const unsigned short* Bptr1 = Bt + (size_t)(bn0 + srow + 64) * ldb + kbeg + scol;

  unsigned short* AsW0 = As + w * 512;
  unsigned short* AsW1 = As + 2048 + w * 512;
  unsigned short* BsW0 = Bs + w * 512;
  unsigned short* BsW1 = Bs + 2048 + w * 512;

  const int fr = lane & 15;
  const int fq = lane >> 4;
  const unsigned short* ArdBase = As + (wr * 64 + fr) * 32 + fq * 8;
  const unsigned short* BrdBase = Bs + (wc * 64 + fr) * 32 + fq * 8;

  for (int kt = 0; kt < nK; ++kt) {
    __syncthreads();
    gld_lds16(Aptr0, AsW0);
    gld_lds16(Aptr1, AsW1);
    gld_lds16(Bptr0, BsW0);
    gld_lds16(Bptr1, BsW1);
    __syncthreads();

    bf16x8 a[4], b[4];
    #pragma unroll
    for (int i = 0; i < 4; ++i) {
      a[i] = *(const bf16x8*)(ArdBase + i * 512);
      b[i] = *(const bf16x8*)(BrdBase + i * 512);
    }
    #pragma unroll
    for (int mi = 0; mi < 4; ++mi)
      #pragma unroll
      for (int ni = 0; ni < 4; ++ni)
        acc[mi][ni] = __builtin_amdgcn_mfma_f32_16x16x32_bf16(
            a[mi], b[ni], acc[mi][ni], 0, 0, 0);

    Aptr0 += 32; Aptr1 += 32; Bptr0 += 32; Bptr1 += 32;
  }

  // epilogue: C/D layout col = lane&15, row = (lane>>4)*4 + reg
  const int row0 = bm0 + wr * 64 + fq * 4;
  const int col0 = bn0 + wc * 64 + fr;
  const size_t zoff = (EPI == EPI_PART) ? (size_t)blockIdx.z * M * N : 0;
  #pragma unroll
  for (int ni = 0; ni < 4; ++ni) {
    const int col = col0 + ni * 16;
    float bval = 0.f;
    if (EPI == EPI_QKV || EPI == EPI_FF1) bval = bias[col];
    #pragma unroll
    for (int mi = 0; mi < 4; ++mi) {
      #pragma unroll
      for (int j = 0; j < 4; ++j) {
        const int row = row0 + mi * 16 + j;
        const size_t idx = zoff + (size_t)row * N + col;
        const float c = acc[mi][ni][j];
        if (EPI == EPI_QKV) {
          Cb[idx] = f2bf(c + bval);
        } else if (EPI == EPI_SC) {
          Cf[idx] = c * scale;
        } else if (EPI == EPI_FF1) {
          const float r = c + bval;
          Cb[idx] = f2bf(r > 0.f ? r : 0.f);
        } else {  // EPI_PART: raw fp32 partial
          Cf[idx] = c;
        }
      }
    }
  }
}

// ---------------------------------------------------------------------------
// out = P0 + P1 + res (+bias).  FINAL=false: write fp32 h + bf16 hb.
// FINAL=true: write fp32 out only (bias per column, N=1024).
// ---------------------------------------------------------------------------
template <bool FINAL>
__global__ void reduce2(const float* __restrict__ P,
                        const float* __restrict__ res,
                        const float* __restrict__ bias,
                        float* __restrict__ outf,
                        unsigned short* __restrict__ outb, long n) {
  long i = ((long)blockIdx.x * 256 + threadIdx.x) * 4;
  if (i >= n) return;
  f32x4 a = *(const f32x4*)(P + i);
  f32x4 b = *(const f32x4*)(P + n + i);
  f32x4 r = *(const f32x4*)(res + i);
  f32x4 o;
  if (FINAL) {
    f32x4 bb = *(const f32x4*)(bias + (i & (DM - 1)));
    #pragma unroll
    for (int j = 0; j < 4; ++j) o[j] = a[j] + b[j] + r[j] + bb[j];
    *(f32x4*)(outf + i) = o;
  } else {
    us4 ob;
    #pragma unroll
    for (int j = 0; j < 4; ++j) { o[j] = a[j] + b[j] + r[j]; ob[j] = f2bf(o[j]); }
    *(f32x4*)(outf + i) = o;
    *(us4*)(outb + i) = ob;
  }
}

// ---------------------------------------------------------------------------
__global__ void softmax_rows(float* __restrict__ sc,
                             unsigned short* __restrict__ attnb) {
  const int m = blockIdx.x;
  const int tid = threadIdx.x;
  const int valid = m + 1;
  float* rowf = sc + (size_t)m * S;
  unsigned short* rowb = attnb + (size_t)m * S;

  f32x4 v[4];
  float lmax = -1e30f;
  #pragma unroll
  for (int i = 0; i < 4; ++i) {
    const int idx = tid * 4 + i * 1024;
    v[i] = *(const f32x4*)(rowf + idx);
    #pragma unroll
    for (int j = 0; j < 4; ++j)
      if (idx + j < valid) lmax = fmaxf(lmax, v[i][j]);
  }
  #pragma unroll
  for (int off = 32; off > 0; off >>= 1)
    lmax = fmaxf(lmax, __shfl_xor(lmax, off, 64));

  __shared__ float red[8];
  if ((tid & 63) == 0) red[tid >> 6] = lmax;
  __syncthreads();
  lmax = fmaxf(fmaxf(red[0], red[1]), fmaxf(red[2], red[3]));

  f32x4 e[4];
  float lsum = 0.f;
  #pragma unroll
  for (int i = 0; i < 4; ++i) {
    const int idx = tid * 4 + i * 1024;
    #pragma unroll
    for (int j = 0; j < 4; ++j) {
      const float ev = (idx + j < valid) ? __expf(v[i][j] - lmax) : 0.f;
      e[i][j] = ev;
      lsum += ev;
    }
  }
  #pragma unroll
  for (int off = 32; off > 0; off >>= 1)
    lsum += __shfl_xor(lsum, off, 64);
  if ((tid & 63) == 0) red[4 + (tid >> 6)] = lsum;
  __syncthreads();
  const float tsum = red[4] + red[5] + red[6] + red[7];
  const float inv = 1.0f / tsum;

  #pragma unroll
  for (int i = 0; i < 4; ++i) {
    const int idx = tid * 4 + i * 1024;
    f32x4 o; us4 ob;
    #pragma unroll
    for (int j = 0; j < 4; ++j) {
      const float t = e[i][j] * inv;
      o[j] = t;
      ob[j] = f2bf(t);
    }
    *(f32x4*)(rowf + idx) = o;
    *(us4*)(rowb + idx) = ob;
  }
}

// ---------------------------------------------------------------------------
extern "C" void kernel_launch(void* const* d_in, const int* in_sizes, int n_in,
                              void* d_out, int out_size, void* d_ws, size_t ws_size,
                              hipStream_t stream) {
  const float* x  = (const float*)d_in[0];
  const float* Wq = (const float*)d_in[1];
  const float* bq = (const float*)d_in[2];
  const float* Wk = (const float*)d_in[3];
  const float* bk = (const float*)d_in[4];
  const float* Wv = (const float*)d_in[5];
  const float* bv = (const float*)d_in[6];
  const float* W1 = (const float*)d_in[7];
  const float* b1 = (const float*)d_in[8];
  const float* W2 = (const float*)d_in[9];
  const float* b2 = (const float*)d_in[10];
  (void)in_sizes; (void)n_in; (void)out_size; (void)ws_size;

  float* outp  = (float*)d_out;                       // [S, DM]
  float* attnf = (float*)d_out + (size_t)S * DM;      // [S, S]

  const size_t MB = 1ull << 20;
  char* ws = (char*)d_ws;
  // phase-overlaid layout (peak 120 MB):
  unsigned short* xb    = (unsigned short*)(ws + 0 * MB);    // [S,DM]      ph1-2
  unsigned short* Wqkvt = (unsigned short*)(ws + 8 * MB);    // [3072,DM]   ph1-2
  float*          bqkv  = (float*)(ws + 14 * MB);            // [3072]      ph1-2
  unsigned short* qkv   = (unsigned short*)(ws + 16 * MB);   // [S,3072]    ph2-3
  float*          P0    = (float*)(ws + 0 * MB);             // [2][S,DM]   ph5,7
  unsigned short* vt    = (unsigned short*)(ws + 40 * MB);   // [DM,S]      ph2-5
  unsigned short* attnb = (unsigned short*)(ws + 48 * MB);   // [S,S]       ph4-5
  float*          h     = (float*)(ws + 80 * MB);            // [S,DM]      ph5-7
  unsigned short* hb    = (unsigned short*)(ws + 96 * MB);   // [S,DM]      ph5-6
  unsigned short* W1t   = (unsigned short*)(ws + 104 * MB);  // [DI,DM]     ph1-6
  unsigned short* W2t   = (unsigned short*)(ws + 112 * MB);  // [DM,DI]     ph1-7
  unsigned short* ff1b  = (unsigned short*)(ws + 40 * MB);   // [S,DI]      ph6-7

  // --- phase 1: converts / transposes / bias concat
  cvt_f32_bf16<<<dim3((S * DM) / (256 * 8)), 256, 0, stream>>>(x, xb, (long)S * DM);
  transpose_cvt<<<dim3(DM / 32, DM / 32), dim3(32, 8), 0, stream>>>(Wq, Wqkvt, DM, DM);
  transpose_cvt<<<dim3(DM / 32, DM / 32), dim3(32, 8), 0, stream>>>(Wk, Wqkvt + (size_t)DM * DM, DM, DM);
  transpose_cvt<<<dim3(DM / 32, DM / 32), dim3(32, 8), 0, stream>>>(Wv, Wqkvt + 2 * (size_t)DM * DM, DM, DM);
  transpose_cvt<<<dim3(DI / 32, DM / 32), dim3(32, 8), 0, stream>>>(W1, W1t, DM, DI);
  transpose_cvt<<<dim3(DM / 32, DI / 32), dim3(32, 8), 0, stream>>>(W2, W2t, DI, DM);
  hipMemcpyAsync(bqkv,          bq, DM * sizeof(float), hipMemcpyDeviceToDevice, stream);
  hipMemcpyAsync(bqkv + DM,     bk, DM * sizeof(float), hipMemcpyDeviceToDevice, stream);
  hipMemcpyAsync(bqkv + 2 * DM, bv, DM * sizeof(float), hipMemcpyDeviceToDevice, stream);

  // --- phase 2: fused QKV projection  qkv[S,3072]
  gemm_bt<EPI_QKV, false, false><<<dim3(3072 / 128, S / 128, 1), 256, 0, stream>>>(
      xb, Wqkvt, S, 3072, DM, DM, DM, DM, bqkv, nullptr, qkv, 1.f);
  // v slice -> vt[DM,S]
  transpose_bf16<<<dim3(DM / 32, S / 32), dim3(32, 8), 0, stream>>>(
      qkv + 2 * DM, 3072, vt, S);

  // --- phase 3: scores = q @ k^T / 32, packed lower-triangular grid
  gemm_bt<EPI_SC, true, false><<<dim3(528, 1, 1), 256, 0, stream>>>(
      qkv, qkv + DM, S, S, DM, 3072, 3072, DM, nullptr, attnf, nullptr, 0.03125f);

  // --- phase 4: causal softmax (fp32 in d_out) + bf16 copy
  softmax_rows<<<dim3(S), 256, 0, stream>>>(attnf, attnb);

  // --- phase 5: attended = attn @ v  (split-K=2, tri-truncated) + reduce
  gemm_bt<EPI_PART, false, true><<<dim3(DM / 128, S / 128, 2), 256, 0, stream>>>(
      attnb, vt, S, DM, S, S, S, S / 2, nullptr, P0, nullptr, 1.f);
  reduce2<false><<<dim3((S * DM) / (256 * 4)), 256, 0, stream>>>(
      P0, x, nullptr, h, hb, (long)S * DM);

  // --- phase 6: ff1 = relu(h @ W1 + b1)
  gemm_bt<EPI_FF1, false, false><<<dim3(DI / 128, S / 128, 1), 256, 0, stream>>>(
      hb, W1t, S, DI, DM, DM, DM, DM, b1, nullptr, ff1b, 1.f);

  // --- phase 7: out = h + ff1 @ W2 + b2  (split-K=2) + final reduce
  gemm_bt<EPI_PART, false, false><<<dim3(DM / 128, S / 128, 2), 256, 0, stream>>>(
      ff1b, W2t, S, DM, DI, DI, DI, DI / 2, nullptr, P0, nullptr, 1.f);
  reduce2<true><<<dim3((S * DM) / (256 * 4)), 256, 0, stream>>>(
      P0, h, b2, outp, nullptr, (long)S * DM);
}

// Round 6
// 286.330 us; speedup vs baseline: 1.4660x; 1.1536x over previous
//
#include <hip/hip_runtime.h>
#include <hip/hip_bf16.h>

// ---------------------------------------------------------------------------
// TransformerLayer on MI355X (gfx950). Round 6 — identical code to Round 3
// (rounds 3/4/5 all died pre-execution: broker kept routing to a dead
// container; source hash bumped via this comment only). 256x256
// deep-pipelined bf16 MFMA GEMM (8 waves, BK=32, 4 LDS slots, counted vmcnt,
// swizzled LDS), fused QKV, packed-tri scores, tri-truncated split-K PV,
// split-K FF2.
// ---------------------------------------------------------------------------

typedef __attribute__((ext_vector_type(4))) float  f32x4;
typedef __attribute__((ext_vector_type(8))) short  bf16x8;
typedef __attribute__((ext_vector_type(4))) unsigned short us4;
typedef __attribute__((ext_vector_type(8))) unsigned short us8;

#define DEVINL __device__ __forceinline__

static constexpr int S   = 4096;
static constexpr int DM  = 1024;
static constexpr int DI  = 4096;

DEVINL unsigned short f2bf(float f) {
  union { float f; unsigned u; } v; v.f = f;
  unsigned r = v.u + 0x7fffu + ((v.u >> 16) & 1u);   // RNE
  return (unsigned short)(r >> 16);
}

DEVINL void gld_lds16(const unsigned short* g, unsigned short* l) {
  __builtin_amdgcn_global_load_lds(
      (const __attribute__((address_space(1))) void*)g,
      (__attribute__((address_space(3))) void*)l,
      16, 0, 0);
}

// ---------------------------------------------------------------------------
__global__ void cvt_f32_bf16(const float* __restrict__ in,
                             unsigned short* __restrict__ out, long n) {
  long i = ((long)blockIdx.x * 256 + threadIdx.x) * 8;
  if (i >= n) return;
  f32x4 a = *(const f32x4*)(in + i);
  f32x4 b = *(const f32x4*)(in + i + 4);
  us8 o;
  o[0] = f2bf(a[0]); o[1] = f2bf(a[1]); o[2] = f2bf(a[2]); o[3] = f2bf(a[3]);
  o[4] = f2bf(b[0]); o[5] = f2bf(b[1]); o[6] = f2bf(b[2]); o[7] = f2bf(b[3]);
  *(us8*)(out + i) = o;
}

// fp32 [R][C] -> bf16 [C][R]
__global__ void transpose_cvt(const float* __restrict__ in,
                              unsigned short* __restrict__ out, int R, int C) {
  __shared__ float tile[32][33];
  const int bx = blockIdx.x * 32, by = blockIdx.y * 32;
  const int tx = threadIdx.x, ty = threadIdx.y;
  #pragma unroll
  for (int j = 0; j < 4; ++j) {
    int r = ty + j * 8;
    tile[r][tx] = in[(size_t)(by + r) * C + bx + tx];
  }
  __syncthreads();
  #pragma unroll
  for (int j = 0; j < 4; ++j) {
    int r = ty + j * 8;
    out[(size_t)(bx + r) * R + by + tx] = f2bf(tile[tx][r]);
  }
}

// bf16 [R][C] (row stride ld) -> out[c*ldo + r]
__global__ void transpose_bf16(const unsigned short* __restrict__ in, int ld,
                               unsigned short* __restrict__ out, int ldo) {
  __shared__ unsigned short tile[32][33];
  const int bx = blockIdx.x * 32, by = blockIdx.y * 32;
  const int tx = threadIdx.x, ty = threadIdx.y;
  #pragma unroll
  for (int j = 0; j < 4; ++j) {
    int r = ty + j * 8;
    tile[r][tx] = in[(size_t)(by + r) * ld + bx + tx];
  }
  __syncthreads();
  #pragma unroll
  for (int j = 0; j < 4; ++j) {
    int r = ty + j * 8;
    out[(size_t)(bx + r) * ldo + by + tx] = tile[tx][r];
  }
}

// ---------------------------------------------------------------------------
// 256x256 tile, BK=32, 512 thr (8 waves, 2Mx4N), 4 LDS slots (128 KB),
// 3-deep staging pipeline with counted vmcnt; XOR-swizzled LDS.
// C = A[M,K](lda) @ Bt[N,K](ldb)^T.
// ---------------------------------------------------------------------------
enum { EPI_QKV = 0, EPI_SC = 2, EPI_FF1 = 4, EPI_PART = 6 };

template <int EPI, bool TRI_PACK, bool TRI_TRUNC>
__launch_bounds__(512, 2)
__global__ void gemm8(const unsigned short* __restrict__ A,
                      const unsigned short* __restrict__ Bt,
                      int M, int N, int K, int lda, int ldb, int kChunk,
                      const float* __restrict__ bias,
                      float* __restrict__ Cf,
                      unsigned short* __restrict__ Cb,
                      float scale) {
  int bm, bn;
  if (TRI_PACK) {
    int t = blockIdx.x;
    bm = (int)((sqrtf(8.f * (float)t + 1.f) - 1.f) * 0.5f);
    while ((bm + 1) * (bm + 2) / 2 <= t) ++bm;
    while (bm * (bm + 1) / 2 > t) --bm;
    bn = t - bm * (bm + 1) / 2;
  } else { bm = blockIdx.y; bn = blockIdx.x; }
  const int bm0 = bm * 256, bn0 = bn * 256;

  const int kbeg = blockIdx.z * kChunk;
  int kend = min(K, kbeg + kChunk);
  if (TRI_TRUNC) kend = min(kend, bm0 + 256);
  const int NT = (kend - kbeg) >> 5;          // BK=32 tiles; may be <= 0

  // 4 slots x (A[256][32] ++ B[256][32]) bf16 = 4 x 32 KB = 128 KB
  __shared__ __align__(16) unsigned short lds[4 * 16384];

  const int tid  = threadIdx.x;
  const int lane = tid & 63;
  const int w    = tid >> 6;                  // wave 0..7
  const int wr   = w >> 2, wc = w & 3;        // 2 x 4 wave grid
  const int fr   = lane & 15, fq = lane >> 4;

  f32x4 acc[8][4] = {};

  // ---- staging addresses (global source carries the inverse swizzle) ----
  const int tq = tid >> 2;                               // row-in-half 0..127
  const int swcolE = ((tid & 3) * 8) ^ ((tq & 6) << 2);  // swizzled col (elems)
  const unsigned short* gA0 = A  + (size_t)(bm0 + tq)       * lda + kbeg + swcolE;
  const unsigned short* gA1 = A  + (size_t)(bm0 + 128 + tq) * lda + kbeg + swcolE;
  const unsigned short* gB0 = Bt + (size_t)(bn0 + tq)       * ldb + kbeg + swcolE;
  const unsigned short* gB1 = Bt + (size_t)(bn0 + 128 + tq) * ldb + kbeg + swcolE;

  auto stageA = [&](int t_) {
    const int s_ = (t_ & 3) * 16384;
    gld_lds16(gA0 + (size_t)t_ * 32, (unsigned short*)lds + s_ + w * 512);
    gld_lds16(gA1 + (size_t)t_ * 32, (unsigned short*)lds + s_ + 4096 + w * 512);
  };
  auto stageB = [&](int t_) {
    const int s_ = (t_ & 3) * 16384;
    gld_lds16(gB0 + (size_t)t_ * 32, (unsigned short*)lds + s_ + 8192 + w * 512);
    gld_lds16(gB1 + (size_t)t_ * 32, (unsigned short*)lds + s_ + 12288 + w * 512);
  };

  // ---- fragment read offset (swizzled) ----
  const int aoffE = fr * 32 + ((fq * 8) ^ ((fr & 6) << 2));

  if (NT > 0) {
    // prologue: stage tiles 0,1,2
    stageA(0); stageB(0);
    if (NT > 1) { stageA(1); stageB(1); }
    if (NT > 2) { stageA(2); stageB(2); }
    if (NT > 2)      { asm volatile("s_waitcnt vmcnt(8)" ::: "memory"); }
    else if (NT > 1) { asm volatile("s_waitcnt vmcnt(4)" ::: "memory"); }
    else             { asm volatile("s_waitcnt vmcnt(0)" ::: "memory"); }
    __builtin_amdgcn_sched_barrier(0);
    __builtin_amdgcn_s_barrier();

    for (int t = 0; t < NT; ++t) {
      const unsigned short* sA = lds + (t & 3) * 16384;
      const unsigned short* sB = sA + 8192;

      // ---- phase 0: m-half 0 ----
      bf16x8 bfrag[4], afrag[4];
      #pragma unroll
      for (int ni = 0; ni < 4; ++ni)
        bfrag[ni] = *(const bf16x8*)(sB + (wc * 64 + ni * 16) * 32 + aoffE);
      #pragma unroll
      for (int mi = 0; mi < 4; ++mi)
        afrag[mi] = *(const bf16x8*)(sA + (wr * 128 + mi * 16) * 32 + aoffE);
      if (t + 3 < NT) stageA(t + 3);
      __builtin_amdgcn_s_barrier();
      __builtin_amdgcn_s_setprio(1);
      #pragma unroll
      for (int mi = 0; mi < 4; ++mi)
        #pragma unroll
        for (int ni = 0; ni < 4; ++ni)
          acc[mi][ni] = __builtin_amdgcn_mfma_f32_16x16x32_bf16(
              afrag[mi], bfrag[ni], acc[mi][ni], 0, 0, 0);
      __builtin_amdgcn_s_setprio(0);
      __builtin_amdgcn_s_barrier();

      // ---- phase 1: m-half 1 (B frags reused in regs) ----
      #pragma unroll
      for (int mi = 0; mi < 4; ++mi)
        afrag[mi] = *(const bf16x8*)(sA + (wr * 128 + 64 + mi * 16) * 32 + aoffE);
      if (t + 3 < NT) {
        stageB(t + 3);
        asm volatile("s_waitcnt vmcnt(8)" ::: "memory");
      } else if (t + 2 < NT) {
        asm volatile("s_waitcnt vmcnt(4)" ::: "memory");
      } else if (t + 1 < NT) {
        asm volatile("s_waitcnt vmcnt(0)" ::: "memory");
      }
      __builtin_amdgcn_sched_barrier(0);
      __builtin_amdgcn_s_barrier();
      __builtin_amdgcn_s_setprio(1);
      #pragma unroll
      for (int mi = 0; mi < 4; ++mi)
        #pragma unroll
        for (int ni = 0; ni < 4; ++ni)
          acc[4 + mi][ni] = __builtin_amdgcn_mfma_f32_16x16x32_bf16(
              afrag[mi], bfrag[ni], acc[4 + mi][ni], 0, 0, 0);
      __builtin_amdgcn_s_setprio(0);
      __builtin_amdgcn_s_barrier();
    }
  }

  // ---- epilogue: C/D layout col = lane&15, row = (lane>>4)*4 + reg ----
  const int row0 = bm0 + wr * 128 + fq * 4;
  const int col0 = bn0 + wc * 64 + fr;
  const size_t zoff = (EPI == EPI_PART) ? (size_t)blockIdx.z * M * N : 0;
  #pragma unroll
  for (int ni = 0; ni < 4; ++ni) {
    const int col = col0 + ni * 16;
    float bval = 0.f;
    if (EPI == EPI_QKV || EPI == EPI_FF1) bval = bias[col];
    #pragma unroll
    for (int a = 0; a < 8; ++a) {
      const int rbase = row0 + (a >> 2) * 64 + (a & 3) * 16;
      #pragma unroll
      for (int j = 0; j < 4; ++j) {
        const int row = rbase + j;
        const size_t idx = zoff + (size_t)row * N + col;
        const float c = acc[a][ni][j];
        if (EPI == EPI_QKV) {
          Cb[idx] = f2bf(c + bval);
        } else if (EPI == EPI_SC) {
          Cf[idx] = c * scale;
        } else if (EPI == EPI_FF1) {
          const float r = c + bval;
          Cb[idx] = f2bf(r > 0.f ? r : 0.f);
        } else {  // EPI_PART
          Cf[idx] = c;
        }
      }
    }
  }
}

// ---------------------------------------------------------------------------
// out = sum_z P[z] + res (+bias). FINAL=false: write fp32 h + bf16 hb.
// ---------------------------------------------------------------------------
template <bool FINAL, int Z>
__global__ void reduce_k(const float* __restrict__ P,
                         const float* __restrict__ res,
                         const float* __restrict__ bias,
                         float* __restrict__ outf,
                         unsigned short* __restrict__ outb, long n) {
  long i = ((long)blockIdx.x * 256 + threadIdx.x) * 4;
  if (i >= n) return;
  f32x4 a = *(const f32x4*)(P + i);
  #pragma unroll
  for (int z = 1; z < Z; ++z) {
    f32x4 b = *(const f32x4*)(P + (size_t)z * n + i);
    #pragma unroll
    for (int j = 0; j < 4; ++j) a[j] += b[j];
  }
  f32x4 r = *(const f32x4*)(res + i);
  if (FINAL) {
    f32x4 bb = *(const f32x4*)(bias + (i & (DM - 1)));
    f32x4 o;
    #pragma unroll
    for (int j = 0; j < 4; ++j) o[j] = a[j] + r[j] + bb[j];
    *(f32x4*)(outf + i) = o;
  } else {
    f32x4 o; us4 ob;
    #pragma unroll
    for (int j = 0; j < 4; ++j) { o[j] = a[j] + r[j]; ob[j] = f2bf(o[j]); }
    *(f32x4*)(outf + i) = o;
    *(us4*)(outb + i) = ob;
  }
}

// ---------------------------------------------------------------------------
__global__ void softmax_rows(float* __restrict__ sc,
                             unsigned short* __restrict__ attnb) {
  const int m = blockIdx.x;
  const int tid = threadIdx.x;
  const int valid = m + 1;
  float* rowf = sc + (size_t)m * S;
  unsigned short* rowb = attnb + (size_t)m * S;

  f32x4 v[4];
  float lmax = -1e30f;
  #pragma unroll
  for (int i = 0; i < 4; ++i) {
    if (i * 1024 <= m) {
      const int idx = tid * 4 + i * 1024;
      v[i] = *(const f32x4*)(rowf + idx);
      #pragma unroll
      for (int j = 0; j < 4; ++j)
        if (idx + j < valid) lmax = fmaxf(lmax, v[i][j]);
    }
  }
  #pragma unroll
  for (int off = 32; off > 0; off >>= 1)
    lmax = fmaxf(lmax, __shfl_xor(lmax, off, 64));

  __shared__ float red[8];
  if ((tid & 63) == 0) red[tid >> 6] = lmax;
  __syncthreads();
  lmax = fmaxf(fmaxf(red[0], red[1]), fmaxf(red[2], red[3]));

  f32x4 e[4];
  float lsum = 0.f;
  #pragma unroll
  for (int i = 0; i < 4; ++i) {
    const int idx = tid * 4 + i * 1024;
    #pragma unroll
    for (int j = 0; j < 4; ++j) e[i][j] = 0.f;
    if (i * 1024 <= m) {
      #pragma unroll
      for (int j = 0; j < 4; ++j) {
        const float ev = (idx + j < valid) ? __expf(v[i][j] - lmax) : 0.f;
        e[i][j] = ev;
        lsum += ev;
      }
    }
  }
  #pragma unroll
  for (int off = 32; off > 0; off >>= 1)
    lsum += __shfl_xor(lsum, off, 64);
  if ((tid & 63) == 0) red[4 + (tid >> 6)] = lsum;
  __syncthreads();
  const float tsum = red[4] + red[5] + red[6] + red[7];
  const float inv = 1.0f / tsum;

  #pragma unroll
  for (int i = 0; i < 4; ++i) {
    const int idx = tid * 4 + i * 1024;
    f32x4 o; us4 ob;
    #pragma unroll
    for (int j = 0; j < 4; ++j) {
      const float t = e[i][j] * inv;
      o[j] = t;
      ob[j] = f2bf(t);
    }
    *(f32x4*)(rowf + idx) = o;
    *(us4*)(rowb + idx) = ob;
  }
}

// ---------------------------------------------------------------------------
extern "C" void kernel_launch(void* const* d_in, const int* in_sizes, int n_in,
                              void* d_out, int out_size, void* d_ws, size_t ws_size,
                              hipStream_t stream) {
  const float* x  = (const float*)d_in[0];
  const float* Wq = (const float*)d_in[1];
  const float* bq = (const float*)d_in[2];
  const float* Wk = (const float*)d_in[3];
  const float* bk = (const float*)d_in[4];
  const float* Wv = (const float*)d_in[5];
  const float* bv = (const float*)d_in[6];
  const float* W1 = (const float*)d_in[7];
  const float* b1 = (const float*)d_in[8];
  const float* W2 = (const float*)d_in[9];
  const float* b2 = (const float*)d_in[10];
  (void)in_sizes; (void)n_in; (void)out_size;

  float* outp  = (float*)d_out;                       // [S, DM]
  float* attnf = (float*)d_out + (size_t)S * DM;      // [S, S]

  const size_t MB = 1ull << 20;
  char* ws = (char*)d_ws;
  // lifetimes: phases 1 prep, 2 qkv(+vt), 3 scores, 4 softmax, 5 pv(+reduce),
  //            6 ff1, 7 ff2(+reduce)
  unsigned short* W2t   = (unsigned short*)(ws + 0 * MB);    // [DM,DI]  1->7
  unsigned short* W1t   = (unsigned short*)(ws + 8 * MB);    // [DI,DM]  1->6
  float*          h     = (float*)(ws + 16 * MB);            // [S,DM]   5->7
  unsigned short* hb    = (unsigned short*)(ws + 32 * MB);   // [S,DM]   5->6
  unsigned short* vt    = (unsigned short*)(ws + 40 * MB);   // [DM,S]   2->5
  unsigned short* attnb = (unsigned short*)(ws + 48 * MB);   // [S,S]    4->5
  unsigned short* qkv   = (unsigned short*)(ws + 80 * MB);   // [S,3072] 2->3
  unsigned short* xb    = (unsigned short*)(ws + 104 * MB);  // [S,DM]   1->2
  unsigned short* Wqkvt = (unsigned short*)(ws + 112 * MB);  // [3072,DM]1->2
  float*          bqkv  = (float*)(ws + 118 * MB);           // [3072]   1->2
  unsigned short* ff1b  = (unsigned short*)(ws + 40 * MB);   // [S,DI]   6->7 (over vt+attnb)
  float*          Ppv   = (float*)(ws + 80 * MB);            // [z][S,DM] ph5
  float*          Pff   = (float*)(ws + 72 * MB);            // [z][S,DM] ph7

  const bool big = ws_size >= 145 * MB;   // z=4 partials fit?

  // --- phase 1: converts / transposes / bias concat
  cvt_f32_bf16<<<dim3((S * DM) / 2048), 256, 0, stream>>>(x, xb, (long)S * DM);
  transpose_cvt<<<dim3(DM / 32, DM / 32), dim3(32, 8), 0, stream>>>(Wq, Wqkvt, DM, DM);
  transpose_cvt<<<dim3(DM / 32, DM / 32), dim3(32, 8), 0, stream>>>(Wk, Wqkvt + (size_t)DM * DM, DM, DM);
  transpose_cvt<<<dim3(DM / 32, DM / 32), dim3(32, 8), 0, stream>>>(Wv, Wqkvt + 2 * (size_t)DM * DM, DM, DM);
  transpose_cvt<<<dim3(DI / 32, DM / 32), dim3(32, 8), 0, stream>>>(W1, W1t, DM, DI);
  transpose_cvt<<<dim3(DM / 32, DI / 32), dim3(32, 8), 0, stream>>>(W2, W2t, DI, DM);
  hipMemcpyAsync(bqkv,          bq, DM * sizeof(float), hipMemcpyDeviceToDevice, stream);
  hipMemcpyAsync(bqkv + DM,     bk, DM * sizeof(float), hipMemcpyDeviceToDevice, stream);
  hipMemcpyAsync(bqkv + 2 * DM, bv, DM * sizeof(float), hipMemcpyDeviceToDevice, stream);

  // --- phase 2: fused QKV projection, then v -> vt
  gemm8<EPI_QKV, false, false><<<dim3(3072 / 256, S / 256, 1), 512, 0, stream>>>(
      xb, Wqkvt, S, 3072, DM, DM, DM, DM, bqkv, nullptr, qkv, 1.f);
  transpose_bf16<<<dim3(DM / 32, S / 32), dim3(32, 8), 0, stream>>>(
      qkv + 2 * DM, 3072, vt, S);

  // --- phase 3: scores = q @ k^T / 32 (packed lower-tri grid, 136 blocks)
  gemm8<EPI_SC, true, false><<<dim3(136, 1, 1), 512, 0, stream>>>(
      qkv, qkv + DM, S, S, DM, 3072, 3072, DM, nullptr, attnf, nullptr, 0.03125f);

  // --- phase 4: causal softmax (fp32 in d_out) + bf16 copy
  softmax_rows<<<dim3(S), 256, 0, stream>>>(attnf, attnb);

  // --- phase 5: attended = attn @ v (tri-truncated, split-K) + reduce -> h, hb
  if (big) {
    gemm8<EPI_PART, false, true><<<dim3(DM / 256, S / 256, 4), 512, 0, stream>>>(
        attnb, vt, S, DM, S, S, S, S / 4, nullptr, Ppv, nullptr, 1.f);
    reduce_k<false, 4><<<dim3((S * DM) / 1024), 256, 0, stream>>>(
        Ppv, x, nullptr, h, hb, (long)S * DM);
  } else {
    gemm8<EPI_PART, false, true><<<dim3(DM / 256, S / 256, 2), 512, 0, stream>>>(
        attnb, vt, S, DM, S, S, S, S / 2, nullptr, Ppv, nullptr, 1.f);
    reduce_k<false, 2><<<dim3((S * DM) / 1024), 256, 0, stream>>>(
        Ppv, x, nullptr, h, hb, (long)S * DM);
  }

  // --- phase 6: ff1 = relu(h @ W1 + b1)
  gemm8<EPI_FF1, false, false><<<dim3(DI / 256, S / 256, 1), 512, 0, stream>>>(
      hb, W1t, S, DI, DM, DM, DM, DM, b1, nullptr, ff1b, 1.f);

  // --- phase 7: out = h + ff1 @ W2 + b2 (split-K) + final reduce
  if (big) {
    gemm8<EPI_PART, false, false><<<dim3(DM / 256, S / 256, 4), 512, 0, stream>>>(
        ff1b, W2t, S, DM, DI, DI, DI, DI / 4, nullptr, Pff, nullptr, 1.f);
    reduce_k<true, 4><<<dim3((S * DM) / 1024), 256, 0, stream>>>(
        Pff, h, b2, outp, nullptr, (long)S * DM);
  } else {
    gemm8<EPI_PART, false, false><<<dim3(DM / 256, S / 256, 2), 512, 0, stream>>>(
        ff1b, W2t, S, DM, DI, DI, DI, DI / 2, nullptr, Pff, nullptr, 1.f);
    reduce_k<true, 2><<<dim3((S * DM) / 1024), 256, 0, stream>>>(
        Pff, h, b2, outp, nullptr, (long)S * DM);
  }
}